// Round 14
// baseline (170.036 us; speedup 1.0000x reference)
//
#include <hip/hip_runtime.h>
#include <hip/hip_bf16.h>

// GCN via bucketed-CSR gather (no global fine-grain atomics), bf16-compressed
// gather operands, fused two-stage MFMA transform, fused gather2+pool+final:
//   xnb[i] = bf16(x[i]*dinv[i])
//   aggb[d] = bf16(dinv[d]*(xnb[d] + sum_{s in N(d)} xnb[s]))    (fp32 accum)
//   (fused) h1 = bf16(relu(aggb @ W1 + b1)) -> per-wave LDS ->
//           ts = bf16((h1 @ W2) * dinv[row])                     (MFMA both)
//   (fused) h2[d] = dinv[d]*(ts[d] + sum ts[s]) -> per-graph sums (LDS table
//           + sparse global atomics); LAST gatherpool block computes the
//           log_softmax (counter + threadfence + coherent atomic reads)
// Gathers process nodes in within-bucket DEGREE-SORTED order (perm) so each
// wave's node-groups have near-equal edge counts (kills max-of-8/32 Poisson
// divergence); inner loops 2-wide unrolled for MLP.
// Round-9 lesson kept: never fuse the latency-bound random gather with the
// occupancy-sensitive MFMA kernel.

#define THREADS 256
#define NPB 256        // nodes per bucket (shift 8)
#define BSTRIDE 4096   // fixed edge capacity per bucket region
#define CH 4096        // edges per partition block
#define NBMAX 512
#define NGRAPH 128     // graphs (out_size/16)

typedef __attribute__((ext_vector_type(8))) short bf16x8;
typedef __attribute__((ext_vector_type(4))) float f32x4;

__device__ __forceinline__ float bfu_lo(unsigned int u) {
    union { unsigned int i; float f; } v; v.i = u << 16; return v.f;
}
__device__ __forceinline__ float bfu_hi(unsigned int u) {
    union { unsigned int i; float f; } v; v.i = u & 0xffff0000u; return v.f;
}
__device__ __forceinline__ unsigned short f2bf(float f) {
    union { float f; unsigned int i; } v; v.f = f;
    unsigned int r = v.i + 0x7fff + ((v.i >> 16) & 1);  // RNE
    return (unsigned short)(r >> 16);
}
__device__ __forceinline__ unsigned int packbf(float lo, float hi) {
    return (unsigned int)f2bf(lo) | ((unsigned int)f2bf(hi) << 16);
}
__device__ __forceinline__ void unpack8(uint4 u, float* f) {
    f[0] = bfu_lo(u.x); f[1] = bfu_hi(u.x);
    f[2] = bfu_lo(u.y); f[3] = bfu_hi(u.y);
    f[4] = bfu_lo(u.z); f[5] = bfu_hi(u.z);
    f[6] = bfu_lo(u.w); f[7] = bfu_hi(u.w);
}

// Partition edges into fixed-stride bucket regions of ebuf, packed
// (local_dst<<17)|src. dst staged in LDS (single global read); one
// reservation atomic per (block,bucket).
__global__ __launch_bounds__(THREADS) void k_partition(const int* __restrict__ src,
                                                       const int* __restrict__ dst,
                                                       int* __restrict__ bucketCursor,
                                                       unsigned int* __restrict__ ebuf,
                                                       int E, int NB) {
    __shared__ int h[NBMAX];
    __shared__ int base[NBMAX];
    __shared__ int cnt[NBMAX];
    __shared__ int dL[CH];  // 16 KB staged dst
    for (int b = threadIdx.x; b < NBMAX; b += THREADS) { h[b] = 0; cnt[b] = 0; }
    __syncthreads();
    int b0 = blockIdx.x * CH;
    for (int k = 0; k < CH; k += THREADS) {
        int e = b0 + k + threadIdx.x;
        if (e < E) {
            int d = dst[e];
            dL[k + threadIdx.x] = d;
            atomicAdd(&h[d >> 8], 1);
        }
    }
    __syncthreads();
    for (int b = threadIdx.x; b < NB; b += THREADS)
        if (h[b]) base[b] = b * BSTRIDE + atomicAdd(&bucketCursor[b], h[b]);
    __syncthreads();
    for (int k = 0; k < CH; k += THREADS) {
        int e = b0 + k + threadIdx.x;
        if (e < E) {
            int s = src[e];
            int d = dL[k + threadIdx.x];
            int b = d >> 8;
            int i = base[b] + atomicAdd(&cnt[b], 1);
            ebuf[i] = ((unsigned int)(d & (NPB - 1)) << 17) | (unsigned int)s;
        }
    }
}

// One block per bucket (256 nodes): edges staged to LDS during count pass ->
// 1-node/thread scan -> offs/deg/dinv (coalesced) -> deg-counting-sort ->
// perm (within-bucket degree order) -> srcs scatter from LDS -> fused xnb.
__global__ __launch_bounds__(THREADS) void k_bucket_csr(const unsigned int* __restrict__ ebuf,
                                                        const int* __restrict__ bucketCursor,
                                                        const float* __restrict__ x,
                                                        int* __restrict__ offs,
                                                        int* __restrict__ deg,
                                                        int* __restrict__ srcs,
                                                        float* __restrict__ dinv,
                                                        uint4* __restrict__ xnb,
                                                        int* __restrict__ perm,
                                                        int n) {
    __shared__ unsigned int eL[BSTRIDE];  // 16 KB edge staging
    __shared__ int c[NPB];
    __shared__ int cur[NPB];
    __shared__ float dloc[NPB];
    __shared__ int sh[THREADS];
    __shared__ int dbin[64];
    __shared__ int dbase[64];
    const int tid = threadIdx.x;
    const int b = blockIdx.x;
    const int nbase = b * NPB;
    const int w0 = b * BSTRIDE;
    const int cnt_b = bucketCursor[b];
    c[tid] = 0;
    if (tid < 64) dbin[tid] = 0;
    __syncthreads();
    for (int i = tid; i < cnt_b; i += THREADS) {
        unsigned int e = ebuf[w0 + i];
        eL[i] = e;
        atomicAdd(&c[e >> 17], 1);
    }
    __syncthreads();
    int c0 = c[tid];
    sh[tid] = c0;
    int node = nbase + tid;
    int rank = 0, db = 0;
    if (node < n) {
        db = min(c0, 63);
        rank = atomicAdd(&dbin[db], 1);  // count + within-bin rank in one pass
    }
    __syncthreads();
    for (int step = 1; step < THREADS; step <<= 1) {
        int t = (tid >= step) ? sh[tid - step] : 0;
        __syncthreads();
        sh[tid] += t;
        __syncthreads();
    }
    if (tid == 0) {  // tiny serial scan of 64 deg bins
        int run = 0;
        for (int i = 0; i < 64; ++i) { dbase[i] = run; run += dbin[i]; }
    }
    int excl = sh[tid] - c0;  // exclusive prefix of edge counts
    float dv = rsqrtf((float)(c0 + 1));
    dloc[tid] = dv;
    if (node < n) {
        offs[node] = w0 + excl;
        deg[node] = c0;
        dinv[node] = dv;
    }
    cur[tid] = excl;
    __syncthreads();  // publishes cur[] and dbase[]
    if (node < n) perm[nbase + dbase[db] + rank] = node;
    for (int i = tid; i < cnt_b; i += THREADS) {
        unsigned int e = eL[i];
        int pos = w0 + atomicAdd(&cur[e >> 17], 1);
        srcs[pos] = (int)(e & 0x1FFFFu);
    }
    // fused xnb: 8 uint4-chunks per node, 256 nodes, 8 iters per thread
    const float4* X4 = (const float4*)x;
    for (int i = tid; i < NPB * 8; i += THREADS) {
        int ln = i >> 3;
        int node2 = nbase + ln;
        if (node2 >= n) break;  // nodes ascend with i
        int q = i & 7;
        float dd = dloc[ln];
        float4 a = X4[(size_t)node2 * 16 + q * 2];
        float4 bb = X4[(size_t)node2 * 16 + q * 2 + 1];
        uint4 o;
        o.x = packbf(a.x * dd, a.y * dd);
        o.y = packbf(a.z * dd, a.w * dd);
        o.z = packbf(bb.x * dd, bb.y * dd);
        o.w = packbf(bb.z * dd, bb.w * dd);
        xnb[(size_t)node2 * 8 + q] = o;
    }
}

// 8 threads/node (deg-sorted via perm), 8 bf16 each:
// aggb[d] = bf16(dinv[d]*(xnb[d] + sum xnb[s])); 2-wide unrolled gather loop.
__global__ __launch_bounds__(THREADS) void k_gather1(const int* __restrict__ offs,
                                                     const int* __restrict__ deg,
                                                     const int* __restrict__ srcs,
                                                     const float* __restrict__ dinv,
                                                     const uint4* __restrict__ xnb,
                                                     const int* __restrict__ perm,
                                                     uint4* __restrict__ aggb, int n) {
    int idx = blockIdx.x * THREADS + threadIdx.x;
    int nid = idx >> 3;
    if (nid >= n) return;
    int node = perm[nid];
    int q = idx & 7;
    float acc[8];
    unpack8(xnb[(size_t)node * 8 + q], acc);  // self term (pre-scaled by dinv[d])
    int e0 = offs[node], e1 = e0 + deg[node];
    int e = e0;
    for (; e + 1 < e1; e += 2) {
        int s0 = srcs[e], s1 = srcs[e + 1];
        float t0[8], t1[8];
        unpack8(xnb[(size_t)s0 * 8 + q], t0);
        unpack8(xnb[(size_t)s1 * 8 + q], t1);
#pragma unroll
        for (int j = 0; j < 8; ++j) acc[j] += t0[j] + t1[j];
    }
    if (e < e1) {
        int s = srcs[e];
        float t[8];
        unpack8(xnb[(size_t)s * 8 + q], t);
#pragma unroll
        for (int j = 0; j < 8; ++j) acc[j] += t[j];
    }
    float dd = dinv[node];
    uint4 o;
    o.x = packbf(acc[0] * dd, acc[1] * dd);
    o.y = packbf(acc[2] * dd, acc[3] * dd);
    o.z = packbf(acc[4] * dd, acc[5] * dd);
    o.w = packbf(acc[6] * dd, acc[7] * dd);
    aggb[(size_t)node * 8 + q] = o;
}

// Fused conv1-GEMM + conv2-GEMM, all MFMA (h1 never leaves the CU):
//   stage 1: h1_tile(16x128) = relu(aggb_tile @ W1 + b1)  (16 MFMA, D-layout)
//   bounce:  pack bf16 -> per-wave LDS [16][136] -> A-layout ds_read_b128
//   stage 2: ts_tile(16x16) = (h1_tile @ W2)*dinv  (4 MFMA, K=128, bf16 W2)
// W1/W2 fragments + biases in registers; 4 waves x 4 tiles; no barriers.
// Layouts (guide-verified m89/m91): A row=lane&15, k=(lane>>4)*8+j;
// B col=lane&15, k=(lane>>4)*8+j; D col=lane&15, row=(lane>>4)*4+reg.
__global__ __launch_bounds__(THREADS) void k_gemm12m(const unsigned short* __restrict__ aggb,
                                                     const float* __restrict__ W1,
                                                     const float* __restrict__ b1,
                                                     const float* __restrict__ W2,
                                                     const float* __restrict__ dinv,
                                                     unsigned short* __restrict__ ts,
                                                     int n, int ntiles) {
    __shared__ unsigned short h1L[4][16][136];  // 17 KB; per-wave, 16B-aligned rows
    const int wave = threadIdx.x >> 6;
    const int lane = threadIdx.x & 63;
    const int col = lane & 15;
    const int ko = lane >> 4;  // 0..3

    bf16x8 bfr1[2][8];
#pragma unroll
    for (int ks = 0; ks < 2; ++ks)
#pragma unroll
        for (int nt = 0; nt < 8; ++nt) {
            bf16x8 b;
#pragma unroll
            for (int j = 0; j < 8; ++j)
                b[j] = (short)f2bf(W1[(ks * 32 + ko * 8 + j) * 128 + nt * 16 + col]);
            bfr1[ks][nt] = b;
        }
    float bias[8];
#pragma unroll
    for (int nt = 0; nt < 8; ++nt) bias[nt] = b1[nt * 16 + col];
    bf16x8 bfr2[4];
#pragma unroll
    for (int ks = 0; ks < 4; ++ks) {
        bf16x8 b;
#pragma unroll
        for (int j = 0; j < 8; ++j)
            b[j] = (short)f2bf(W2[(ks * 32 + ko * 8 + j) * 16 + col]);
        bfr2[ks] = b;
    }

    const int tile0 = (blockIdx.x * 4 + wave) * 4;  // 4 tiles per wave
    for (int t = 0; t < 4; ++t) {
        int tile = tile0 + t;
        if (tile >= ntiles) return;
        int r0 = tile * 16;
        int rowA = r0 + col;
        if (rowA >= n) rowA = n - 1;  // duplicate last row on ragged tail
        const bf16x8* Ap = (const bf16x8*)(aggb + (size_t)rowA * 64 + ko * 8);
        bf16x8 a0 = Ap[0];
        bf16x8 a1 = Ap[4];
        f32x4 acc[8];
#pragma unroll
        for (int nt = 0; nt < 8; ++nt) acc[nt] = (f32x4){0.f, 0.f, 0.f, 0.f};
#pragma unroll
        for (int nt = 0; nt < 8; ++nt) {
            acc[nt] = __builtin_amdgcn_mfma_f32_16x16x32_bf16(a0, bfr1[0][nt], acc[nt], 0, 0, 0);
            acc[nt] = __builtin_amdgcn_mfma_f32_16x16x32_bf16(a1, bfr1[1][nt], acc[nt], 0, 0, 0);
        }
#pragma unroll
        for (int nt = 0; nt < 8; ++nt)
#pragma unroll
            for (int r = 0; r < 4; ++r)
                h1L[wave][ko * 4 + r][nt * 16 + col] = f2bf(fmaxf(acc[nt][r] + bias[nt], 0.f));
        f32x4 acc2 = (f32x4){0.f, 0.f, 0.f, 0.f};
#pragma unroll
        for (int ks = 0; ks < 4; ++ks) {
            bf16x8 a2 = *(const bf16x8*)&h1L[wave][col][ks * 32 + ko * 8];
            acc2 = __builtin_amdgcn_mfma_f32_16x16x32_bf16(a2, bfr2[ks], acc2, 0, 0, 0);
        }
#pragma unroll
        for (int r = 0; r < 4; ++r) {
            int row = r0 + ko * 4 + r;
            if (row < n) {
                float dd = dinv[row];
                ts[(size_t)row * 16 + col] = f2bf(acc2[r] * dd);
            }
        }
    }
}

// Fused gather2 + mean-pool + (last block) log_softmax. 2 threads/node via
// perm; h2row = dinv[d]*(ts[d] + sum ts[s]) -> per-block LDS [NGRAPH][16]
// table -> sparse global atomic flush. Last block (counter) re-reads sums
// coherently (atomicAdd(p,0)) and writes the final output.
__global__ __launch_bounds__(THREADS) void k_gatherpool(const int* __restrict__ offs,
                                                        const int* __restrict__ deg,
                                                        const int* __restrict__ srcs,
                                                        const float* __restrict__ dinv,
                                                        const uint4* __restrict__ ts,
                                                        const int* __restrict__ batch,
                                                        const int* __restrict__ perm,
                                                        float* __restrict__ sums,
                                                        int* __restrict__ donecnt,
                                                        const float* __restrict__ b2,
                                                        float* __restrict__ out, int n) {
    __shared__ float gsum[NGRAPH * 16];  // 8 KB
    __shared__ int lastFlag;
    const int tid = threadIdx.x;
    for (int i = tid; i < NGRAPH * 16; i += THREADS) gsum[i] = 0.f;
    __syncthreads();
    int idx = blockIdx.x * THREADS + tid;
    int nid = idx >> 1;
    if (nid < n) {
        int node = perm[nid];
        int q = idx & 1;
        float acc[8];
        unpack8(ts[(size_t)node * 2 + q], acc);
        int e0 = offs[node], e1 = e0 + deg[node];
        int e = e0;
        for (; e + 1 < e1; e += 2) {
            int s0 = srcs[e], s1 = srcs[e + 1];
            float t0[8], t1[8];
            unpack8(ts[(size_t)s0 * 2 + q], t0);
            unpack8(ts[(size_t)s1 * 2 + q], t1);
#pragma unroll
            for (int j = 0; j < 8; ++j) acc[j] += t0[j] + t1[j];
        }
        if (e < e1) {
            int s = srcs[e];
            float t[8];
            unpack8(ts[(size_t)s * 2 + q], t);
#pragma unroll
            for (int j = 0; j < 8; ++j) acc[j] += t[j];
        }
        float dd = dinv[node];
        int g = batch[node];
        float* row = &gsum[g * 16 + q * 8];
#pragma unroll
        for (int j = 0; j < 8; ++j) atomicAdd(&row[j], acc[j] * dd);
    }
    __syncthreads();
    for (int i = tid; i < NGRAPH * 16; i += THREADS) {
        float v = gsum[i];
        if (v != 0.f) atomicAdd(&sums[i], v);
    }
    __threadfence();
    if (tid == 0) lastFlag = (atomicAdd(donecnt, 1) == (int)gridDim.x - 1);
    __syncthreads();
    if (lastFlag && tid < NGRAPH) {
        __threadfence();
        int g = tid;
        int lo = 0, hi = n;
        while (lo < hi) { int mid = (lo + hi) >> 1; if (batch[mid] < g) lo = mid + 1; else hi = mid; }
        int s0 = lo;
        hi = n;
        while (lo < hi) { int mid = (lo + hi) >> 1; if (batch[mid] < g + 1) lo = mid + 1; else hi = mid; }
        float cnt = fmaxf((float)(lo - s0), 1.0f);
        float v[16];
        float mx = -1e30f;
#pragma unroll
        for (int c = 0; c < 16; ++c) {
            v[c] = atomicAdd(&sums[g * 16 + c], 0.0f) / cnt + b2[c];  // coherent read
            mx = fmaxf(mx, v[c]);
        }
        float se = 0.f;
#pragma unroll
        for (int c = 0; c < 16; ++c) se += expf(v[c] - mx);
        float lse = logf(se) + mx;
#pragma unroll
        for (int c = 0; c < 16; ++c) out[g * 16 + c] = v[c] - lse;
    }
}

extern "C" void kernel_launch(void* const* d_in, const int* in_sizes, int n_in,
                              void* d_out, int out_size, void* d_ws, size_t ws_size,
                              hipStream_t stream) {
    const float* x    = (const float*)d_in[0];
    const int* edges  = (const int*)d_in[1];
    const int* batch  = (const int*)d_in[2];
    const float* W1   = (const float*)d_in[3];
    const float* b1   = (const float*)d_in[4];
    const float* W2   = (const float*)d_in[5];
    const float* b2   = (const float*)d_in[6];
    float* out        = (float*)d_out;

    const int n = in_sizes[2];
    const int E = in_sizes[1] / 2;
    const int* src = edges;
    const int* dst = edges + E;
    const int NB = (n + NPB - 1) / NPB;             // 391 <= 512
    const int npart = (E + CH - 1) / CH;            // 294
    const int ntiles = (n + 15) / 16;               // 6250

    char* ws = (char*)d_ws;
    size_t off = 0;
    auto carve = [&](size_t bytes) { char* p = ws + off; off = (off + bytes + 255) & ~(size_t)255; return p; };
    int*   bucketCursor = (int*)carve(NBMAX * 4);             // ┐ zeroed by one
    float* sums    = (float*)carve(NGRAPH * 16 * 4);          // │ contiguous
    int*   donecnt = (int*)carve(256);                        // ┘ memset below
    int*   offs    = (int*)carve((size_t)n * 4);
    int*   deg     = (int*)carve((size_t)n * 4);
    int*   perm    = (int*)carve((size_t)n * 4);
    int*   srcs    = (int*)carve((size_t)NB * BSTRIDE * 4);   // 6.4 MB, bucket-strided
    float* dinv    = (float*)carve((size_t)n * 4);
    uint4* xnb     = (uint4*)carve((size_t)n * 64 * 2);       // 12.8 MB bf16
    char*  aggreg  = (char*)carve((size_t)n * 64 * 2);        // aggb bf16
    char*  big     = (char*)carve((size_t)NB * BSTRIDE * 4 > (size_t)n * 128 * 2
                                  ? (size_t)NB * BSTRIDE * 4 : (size_t)n * 128 * 2);
    unsigned int* ebuf = (unsigned int*)big;        // dead after k_bucket_csr
    unsigned short* ts = (unsigned short*)big;      // 3.2 MB, reuses big after ebuf dies
    unsigned short* aggb = (unsigned short*)aggreg;

    auto blks = [](long long work) { return (int)((work + THREADS - 1) / THREADS); };

    hipMemsetAsync(bucketCursor, 0, NBMAX * 4 + NGRAPH * 16 * 4 + 256, stream);
    k_partition  <<<npart, THREADS, 0, stream>>>(src, dst, bucketCursor, ebuf, E, NB);
    k_bucket_csr <<<NB, THREADS, 0, stream>>>(ebuf, bucketCursor, x, offs, deg, srcs, dinv, xnb, perm, n);

    k_gather1 <<<blks((long long)n * 8), THREADS, 0, stream>>>(offs, deg, srcs, dinv, xnb, perm, (uint4*)aggb, n);
    k_gemm12m <<<(ntiles + 15) / 16, THREADS, 0, stream>>>(aggb, W1, b1, W2, dinv, ts, n, ntiles);

    k_gatherpool <<<blks((long long)n * 2), THREADS, 0, stream>>>(offs, deg, srcs, dinv,
                                                                  (const uint4*)ts, batch, perm,
                                                                  sums, donecnt, b2, out, n);
}

// Round 15
// 118.306 us; speedup vs baseline: 1.4373x; 1.4373x over previous
//
#include <hip/hip_runtime.h>
#include <hip/hip_bf16.h>

// GCN via bucketed-CSR gather (no global fine-grain atomics), bf16-compressed
// gather operands, fused two-stage MFMA transform, fused gather2+pool:
//   xnb[i] = bf16(x[i]*dinv[i])
//   aggb[d] = bf16(dinv[d]*(xnb[d] + sum_{s in N(d)} xnb[s]))    (fp32 accum)
//   (fused) h1 = bf16(relu(aggb @ W1 + b1)) -> per-wave LDS ->
//           ts = bf16((h1 @ W2) * dinv[row])                     (MFMA both)
//   (fused) h2[d] = dinv[d]*(ts[d] + sum ts[s]) -> per-graph sums via SMALL
//           LDS table (8 graphs x 16ch, base = batch[block's first node];
//           64-node blocks span <=2 graphs) + sparse global atomic flush
//   out = log_softmax(sums/cnt + b2)   (tiny 1-block kernel)
// Round-9 lesson: never fuse the latency-bound random gather with the MFMA
// kernel. Round-14 lesson: no perm indirection — it uncoalesces every
// per-node access and doubles gatherpool's latency-bound runtime.

#define THREADS 256
#define NPB 256        // nodes per bucket (shift 8)
#define BSTRIDE 4096   // fixed edge capacity per bucket region
#define CH 4096        // edges per partition block
#define NBMAX 512
#define NGRAPH 128     // graphs (out_size/16)

typedef __attribute__((ext_vector_type(8))) short bf16x8;
typedef __attribute__((ext_vector_type(4))) float f32x4;

__device__ __forceinline__ float bfu_lo(unsigned int u) {
    union { unsigned int i; float f; } v; v.i = u << 16; return v.f;
}
__device__ __forceinline__ float bfu_hi(unsigned int u) {
    union { unsigned int i; float f; } v; v.i = u & 0xffff0000u; return v.f;
}
__device__ __forceinline__ unsigned short f2bf(float f) {
    union { float f; unsigned int i; } v; v.f = f;
    unsigned int r = v.i + 0x7fff + ((v.i >> 16) & 1);  // RNE
    return (unsigned short)(r >> 16);
}
__device__ __forceinline__ unsigned int packbf(float lo, float hi) {
    return (unsigned int)f2bf(lo) | ((unsigned int)f2bf(hi) << 16);
}
__device__ __forceinline__ void unpack8(uint4 u, float* f) {
    f[0] = bfu_lo(u.x); f[1] = bfu_hi(u.x);
    f[2] = bfu_lo(u.y); f[3] = bfu_hi(u.y);
    f[4] = bfu_lo(u.z); f[5] = bfu_hi(u.z);
    f[6] = bfu_lo(u.w); f[7] = bfu_hi(u.w);
}
__device__ __forceinline__ void unpack4(uint2 u, float* f) {
    f[0] = bfu_lo(u.x); f[1] = bfu_hi(u.x);
    f[2] = bfu_lo(u.y); f[3] = bfu_hi(u.y);
}

// Partition edges into fixed-stride bucket regions of ebuf, packed
// (local_dst<<17)|src. dst staged in LDS (single global read); one
// reservation atomic per (block,bucket).
__global__ __launch_bounds__(THREADS) void k_partition(const int* __restrict__ src,
                                                       const int* __restrict__ dst,
                                                       int* __restrict__ bucketCursor,
                                                       unsigned int* __restrict__ ebuf,
                                                       int E, int NB) {
    __shared__ int h[NBMAX];
    __shared__ int base[NBMAX];
    __shared__ int cnt[NBMAX];
    __shared__ int dL[CH];  // 16 KB staged dst
    for (int b = threadIdx.x; b < NBMAX; b += THREADS) { h[b] = 0; cnt[b] = 0; }
    __syncthreads();
    int b0 = blockIdx.x * CH;
    for (int k = 0; k < CH; k += THREADS) {
        int e = b0 + k + threadIdx.x;
        if (e < E) {
            int d = dst[e];
            dL[k + threadIdx.x] = d;
            atomicAdd(&h[d >> 8], 1);
        }
    }
    __syncthreads();
    for (int b = threadIdx.x; b < NB; b += THREADS)
        if (h[b]) base[b] = b * BSTRIDE + atomicAdd(&bucketCursor[b], h[b]);
    __syncthreads();
    for (int k = 0; k < CH; k += THREADS) {
        int e = b0 + k + threadIdx.x;
        if (e < E) {
            int s = src[e];
            int d = dL[k + threadIdx.x];
            int b = d >> 8;
            int i = base[b] + atomicAdd(&cnt[b], 1);
            ebuf[i] = ((unsigned int)(d & (NPB - 1)) << 17) | (unsigned int)s;
        }
    }
}

// One block per bucket (256 nodes): edges staged to LDS during count pass ->
// 1-node/thread scan -> offs/deg/dinv (coalesced) -> srcs scatter from LDS via
// LDS cursors -> fused xnb emission (xnb[i] = bf16(x[i]*dinv[i])).
__global__ __launch_bounds__(THREADS) void k_bucket_csr(const unsigned int* __restrict__ ebuf,
                                                        const int* __restrict__ bucketCursor,
                                                        const float* __restrict__ x,
                                                        int* __restrict__ offs,
                                                        int* __restrict__ deg,
                                                        int* __restrict__ srcs,
                                                        float* __restrict__ dinv,
                                                        uint4* __restrict__ xnb,
                                                        int n) {
    __shared__ unsigned int eL[BSTRIDE];  // 16 KB edge staging
    __shared__ int c[NPB];
    __shared__ int cur[NPB];
    __shared__ float dloc[NPB];
    __shared__ int sh[THREADS];
    const int tid = threadIdx.x;
    const int b = blockIdx.x;
    const int nbase = b * NPB;
    const int w0 = b * BSTRIDE;
    const int cnt_b = bucketCursor[b];
    c[tid] = 0;
    __syncthreads();
    for (int i = tid; i < cnt_b; i += THREADS) {
        unsigned int e = ebuf[w0 + i];
        eL[i] = e;
        atomicAdd(&c[e >> 17], 1);
    }
    __syncthreads();
    int c0 = c[tid];
    sh[tid] = c0;
    __syncthreads();
    for (int step = 1; step < THREADS; step <<= 1) {
        int t = (tid >= step) ? sh[tid - step] : 0;
        __syncthreads();
        sh[tid] += t;
        __syncthreads();
    }
    int excl = sh[tid] - c0;  // exclusive prefix
    int node = nbase + tid;
    float dv = rsqrtf((float)(c0 + 1));
    dloc[tid] = dv;
    if (node < n) {
        offs[node] = w0 + excl;
        deg[node] = c0;
        dinv[node] = dv;
    }
    cur[tid] = excl;
    __syncthreads();
    for (int i = tid; i < cnt_b; i += THREADS) {
        unsigned int e = eL[i];
        int pos = w0 + atomicAdd(&cur[e >> 17], 1);
        srcs[pos] = (int)(e & 0x1FFFFu);
    }
    // fused xnb: 8 uint4-chunks per node, 256 nodes, 8 iters per thread
    const float4* X4 = (const float4*)x;
    for (int i = tid; i < NPB * 8; i += THREADS) {
        int ln = i >> 3;
        int node2 = nbase + ln;
        if (node2 >= n) break;  // nodes ascend with i
        int q = i & 7;
        float dd = dloc[ln];
        float4 a = X4[(size_t)node2 * 16 + q * 2];
        float4 bb = X4[(size_t)node2 * 16 + q * 2 + 1];
        uint4 o;
        o.x = packbf(a.x * dd, a.y * dd);
        o.y = packbf(a.z * dd, a.w * dd);
        o.z = packbf(bb.x * dd, bb.y * dd);
        o.w = packbf(bb.z * dd, bb.w * dd);
        xnb[(size_t)node2 * 8 + q] = o;
    }
}

// 8 threads/node (natural order), 8 bf16 each, 2-wide unrolled gather:
// aggb[d] = bf16(dinv[d]*(xnb[d] + sum xnb[s])).
__global__ __launch_bounds__(THREADS) void k_gather1(const int* __restrict__ offs,
                                                     const int* __restrict__ deg,
                                                     const int* __restrict__ srcs,
                                                     const float* __restrict__ dinv,
                                                     const uint4* __restrict__ xnb,
                                                     uint4* __restrict__ aggb, int n) {
    int idx = blockIdx.x * THREADS + threadIdx.x;
    int node = idx >> 3;
    if (node >= n) return;
    int q = idx & 7;
    float acc[8];
    unpack8(xnb[(size_t)node * 8 + q], acc);  // self term (pre-scaled by dinv[d])
    int e0 = offs[node], e1 = e0 + deg[node];
    int e = e0;
    for (; e + 1 < e1; e += 2) {
        int s0 = srcs[e], s1 = srcs[e + 1];
        float t0[8], t1[8];
        unpack8(xnb[(size_t)s0 * 8 + q], t0);
        unpack8(xnb[(size_t)s1 * 8 + q], t1);
#pragma unroll
        for (int j = 0; j < 8; ++j) acc[j] += t0[j] + t1[j];
    }
    if (e < e1) {
        int s = srcs[e];
        float t[8];
        unpack8(xnb[(size_t)s * 8 + q], t);
#pragma unroll
        for (int j = 0; j < 8; ++j) acc[j] += t[j];
    }
    float dd = dinv[node];
    uint4 o;
    o.x = packbf(acc[0] * dd, acc[1] * dd);
    o.y = packbf(acc[2] * dd, acc[3] * dd);
    o.z = packbf(acc[4] * dd, acc[5] * dd);
    o.w = packbf(acc[6] * dd, acc[7] * dd);
    aggb[(size_t)node * 8 + q] = o;
}

// Fused conv1-GEMM + conv2-GEMM, all MFMA (h1 never leaves the CU):
//   stage 1: h1_tile(16x128) = relu(aggb_tile @ W1 + b1)  (16 MFMA, D-layout)
//   bounce:  pack bf16 -> per-wave LDS [16][136] -> A-layout ds_read_b128
//   stage 2: ts_tile(16x16) = (h1_tile @ W2)*dinv  (4 MFMA, K=128, bf16 W2)
// W1/W2 fragments + biases in registers; 4 waves x 4 tiles; no barriers.
// Layouts (guide-verified m89/m91): A row=lane&15, k=(lane>>4)*8+j;
// B col=lane&15, k=(lane>>4)*8+j; D col=lane&15, row=(lane>>4)*4+reg.
__global__ __launch_bounds__(THREADS) void k_gemm12m(const unsigned short* __restrict__ aggb,
                                                     const float* __restrict__ W1,
                                                     const float* __restrict__ b1,
                                                     const float* __restrict__ W2,
                                                     const float* __restrict__ dinv,
                                                     unsigned short* __restrict__ ts,
                                                     int n, int ntiles) {
    __shared__ unsigned short h1L[4][16][136];  // 17 KB; per-wave, 16B-aligned rows
    const int wave = threadIdx.x >> 6;
    const int lane = threadIdx.x & 63;
    const int col = lane & 15;
    const int ko = lane >> 4;  // 0..3

    bf16x8 bfr1[2][8];
#pragma unroll
    for (int ks = 0; ks < 2; ++ks)
#pragma unroll
        for (int nt = 0; nt < 8; ++nt) {
            bf16x8 b;
#pragma unroll
            for (int j = 0; j < 8; ++j)
                b[j] = (short)f2bf(W1[(ks * 32 + ko * 8 + j) * 128 + nt * 16 + col]);
            bfr1[ks][nt] = b;
        }
    float bias[8];
#pragma unroll
    for (int nt = 0; nt < 8; ++nt) bias[nt] = b1[nt * 16 + col];
    bf16x8 bfr2[4];
#pragma unroll
    for (int ks = 0; ks < 4; ++ks) {
        bf16x8 b;
#pragma unroll
        for (int j = 0; j < 8; ++j)
            b[j] = (short)f2bf(W2[(ks * 32 + ko * 8 + j) * 16 + col]);
        bfr2[ks] = b;
    }

    const int tile0 = (blockIdx.x * 4 + wave) * 4;  // 4 tiles per wave
    for (int t = 0; t < 4; ++t) {
        int tile = tile0 + t;
        if (tile >= ntiles) return;
        int r0 = tile * 16;
        int rowA = r0 + col;
        if (rowA >= n) rowA = n - 1;  // duplicate last row on ragged tail
        const bf16x8* Ap = (const bf16x8*)(aggb + (size_t)rowA * 64 + ko * 8);
        bf16x8 a0 = Ap[0];
        bf16x8 a1 = Ap[4];
        f32x4 acc[8];
#pragma unroll
        for (int nt = 0; nt < 8; ++nt) acc[nt] = (f32x4){0.f, 0.f, 0.f, 0.f};
#pragma unroll
        for (int nt = 0; nt < 8; ++nt) {
            acc[nt] = __builtin_amdgcn_mfma_f32_16x16x32_bf16(a0, bfr1[0][nt], acc[nt], 0, 0, 0);
            acc[nt] = __builtin_amdgcn_mfma_f32_16x16x32_bf16(a1, bfr1[1][nt], acc[nt], 0, 0, 0);
        }
#pragma unroll
        for (int nt = 0; nt < 8; ++nt)
#pragma unroll
            for (int r = 0; r < 4; ++r)
                h1L[wave][ko * 4 + r][nt * 16 + col] = f2bf(fmaxf(acc[nt][r] + bias[nt], 0.f));
        f32x4 acc2 = (f32x4){0.f, 0.f, 0.f, 0.f};
#pragma unroll
        for (int ks = 0; ks < 4; ++ks) {
            bf16x8 a2 = *(const bf16x8*)&h1L[wave][col][ks * 32 + ko * 8];
            acc2 = __builtin_amdgcn_mfma_f32_16x16x32_bf16(a2, bfr2[ks], acc2, 0, 0, 0);
        }
#pragma unroll
        for (int r = 0; r < 4; ++r) {
            int row = r0 + ko * 4 + r;
            if (row < n) {
                float dd = dinv[row];
                ts[(size_t)row * 16 + col] = f2bf(acc2[r] * dd);
            }
        }
    }
}

// Fused gather2 + mean-pool. 4 threads/node (uint2 = 4 bf16 each), natural
// node order (coalesced); 2-wide unrolled edge loop. Per-block LDS table is
// only 8 graphs x 16 ch (64-node blocks span <=2 graphs; base graph =
// batch[first node]); overflow falls back to direct global atomics.
__global__ __launch_bounds__(THREADS) void k_gatherpool(const int* __restrict__ offs,
                                                        const int* __restrict__ deg,
                                                        const int* __restrict__ srcs,
                                                        const float* __restrict__ dinv,
                                                        const uint2* __restrict__ ts,
                                                        const int* __restrict__ batch,
                                                        float* __restrict__ sums, int n) {
    __shared__ float gsum[8 * 16];  // 512 B
    __shared__ int gminS;
    const int tid = threadIdx.x;
    if (tid < 128) gsum[tid] = 0.f;
    if (tid == 0) {
        int first = min((blockIdx.x * THREADS) >> 2, n - 1);
        gminS = batch[first];
    }
    __syncthreads();
    const int gmin = gminS;
    int idx = blockIdx.x * THREADS + tid;
    int node = idx >> 2;
    if (node < n) {
        int q = idx & 3;
        float acc[4];
        unpack4(ts[(size_t)node * 4 + q], acc);  // self term
        int e0 = offs[node], e1 = e0 + deg[node];
        int e = e0;
        for (; e + 1 < e1; e += 2) {
            int s0 = srcs[e], s1 = srcs[e + 1];
            float t0[4], t1[4];
            unpack4(ts[(size_t)s0 * 4 + q], t0);
            unpack4(ts[(size_t)s1 * 4 + q], t1);
#pragma unroll
            for (int j = 0; j < 4; ++j) acc[j] += t0[j] + t1[j];
        }
        if (e < e1) {
            int s = srcs[e];
            float t[4];
            unpack4(ts[(size_t)s * 4 + q], t);
#pragma unroll
            for (int j = 0; j < 4; ++j) acc[j] += t[j];
        }
        float dd = dinv[node];
        int g = batch[node];
        int local = g - gmin;
        if ((unsigned)local < 8u) {
            float* row = &gsum[local * 16 + q * 4];
#pragma unroll
            for (int j = 0; j < 4; ++j) atomicAdd(&row[j], acc[j] * dd);
        } else {  // pathological graph-size case: direct global
            float* row = &sums[g * 16 + q * 4];
#pragma unroll
            for (int j = 0; j < 4; ++j) atomicAdd(&row[j], acc[j] * dd);
        }
    }
    __syncthreads();
    if (tid < 128) {
        float v = gsum[tid];
        int g = gmin + (tid >> 4);
        if (v != 0.f && g < NGRAPH) atomicAdd(&sums[g * 16 + (tid & 15)], v);
    }
}

// One tiny block: per-graph count (binary search over sorted batch), mean,
// bias, log_softmax.
__global__ __launch_bounds__(NGRAPH) void k_final(const float* __restrict__ sums,
                                                  const int* __restrict__ batch,
                                                  const float* __restrict__ b2,
                                                  float* __restrict__ out, int n) {
    int g = threadIdx.x;
    int lo = 0, hi = n;
    while (lo < hi) { int mid = (lo + hi) >> 1; if (batch[mid] < g) lo = mid + 1; else hi = mid; }
    int s0 = lo;
    hi = n;
    while (lo < hi) { int mid = (lo + hi) >> 1; if (batch[mid] < g + 1) lo = mid + 1; else hi = mid; }
    int s1 = lo;
    float cnt = fmaxf((float)(s1 - s0), 1.0f);
    float v[16];
    float mx = -1e30f;
#pragma unroll
    for (int c = 0; c < 16; ++c) {
        v[c] = sums[g * 16 + c] / cnt + b2[c];
        mx = fmaxf(mx, v[c]);
    }
    float se = 0.f;
#pragma unroll
    for (int c = 0; c < 16; ++c) se += expf(v[c] - mx);
    float lse = logf(se) + mx;
#pragma unroll
    for (int c = 0; c < 16; ++c) out[g * 16 + c] = v[c] - lse;
}

extern "C" void kernel_launch(void* const* d_in, const int* in_sizes, int n_in,
                              void* d_out, int out_size, void* d_ws, size_t ws_size,
                              hipStream_t stream) {
    const float* x    = (const float*)d_in[0];
    const int* edges  = (const int*)d_in[1];
    const int* batch  = (const int*)d_in[2];
    const float* W1   = (const float*)d_in[3];
    const float* b1   = (const float*)d_in[4];
    const float* W2   = (const float*)d_in[5];
    const float* b2   = (const float*)d_in[6];
    float* out        = (float*)d_out;

    const int n = in_sizes[2];
    const int E = in_sizes[1] / 2;
    const int* src = edges;
    const int* dst = edges + E;
    const int NB = (n + NPB - 1) / NPB;             // 391 <= 512
    const int npart = (E + CH - 1) / CH;            // 294
    const int ntiles = (n + 15) / 16;               // 6250

    char* ws = (char*)d_ws;
    size_t off = 0;
    auto carve = [&](size_t bytes) { char* p = ws + off; off = (off + bytes + 255) & ~(size_t)255; return p; };
    int*   bucketCursor = (int*)carve(NBMAX * 4);             // ┐ zeroed by one
    float* sums    = (float*)carve(NGRAPH * 16 * 4);          // ┘ memset below
    int*   offs    = (int*)carve((size_t)n * 4);
    int*   deg     = (int*)carve((size_t)n * 4);
    int*   srcs    = (int*)carve((size_t)NB * BSTRIDE * 4);   // 6.4 MB, bucket-strided
    float* dinv    = (float*)carve((size_t)n * 4);
    uint4* xnb     = (uint4*)carve((size_t)n * 64 * 2);       // 12.8 MB bf16
    char*  aggreg  = (char*)carve((size_t)n * 64 * 2);        // aggb bf16
    char*  big     = (char*)carve((size_t)NB * BSTRIDE * 4 > (size_t)n * 128 * 2
                                  ? (size_t)NB * BSTRIDE * 4 : (size_t)n * 128 * 2);
    unsigned int* ebuf = (unsigned int*)big;        // dead after k_bucket_csr
    unsigned short* ts = (unsigned short*)big;      // 3.2 MB, reuses big after ebuf dies
    unsigned short* aggb = (unsigned short*)aggreg;

    auto blks = [](long long work) { return (int)((work + THREADS - 1) / THREADS); };

    hipMemsetAsync(bucketCursor, 0, NBMAX * 4 + NGRAPH * 16 * 4, stream);
    k_partition  <<<npart, THREADS, 0, stream>>>(src, dst, bucketCursor, ebuf, E, NB);
    k_bucket_csr <<<NB, THREADS, 0, stream>>>(ebuf, bucketCursor, x, offs, deg, srcs, dinv, xnb, n);

    k_gather1 <<<blks((long long)n * 8), THREADS, 0, stream>>>(offs, deg, srcs, dinv, xnb, (uint4*)aggb, n);
    k_gemm12m <<<(ntiles + 15) / 16, THREADS, 0, stream>>>(aggb, W1, b1, W2, dinv, ts, n, ntiles);

    k_gatherpool <<<blks((long long)n * 4), THREADS, 0, stream>>>(offs, deg, srcs, dinv,
                                                                  (const uint2*)ts, batch, sums, n);
    k_final <<<1, NGRAPH, 0, stream>>>(sums, batch, b2, out, n);
}